// Round 4
// baseline (147.287 us; speedup 1.0000x reference)
//
#include <hip/hip_runtime.h>

#define EPS 1.1920928955078125e-07f

// Problem constants
#define BB 32
#define TT 256000
#define CHUNKS 50                    // chunks per batch element
#define T4 (TT / 4)                  // 64000 float4 per signal
#define CHUNK (T4 / CHUNKS)          // 1280 float4 per block
#define SEGS_PER_WAVE 5              // 5 segments x 64 float4 = 320 f4 per wave; 4 waves = 1280
#define NBLK (BB * CHUNKS)           // 1600 blocks

// 12 per-batch statistics (raw sums; zero-meaning folded in at finalize):
// [0] sum p0   [1] sum p1   [2] sum t0   [3] sum t1
// [4] sum p0^2 [5] sum p1^2 [6] sum t0^2 [7] sum t1^2
// [8] sum p0*t0 [9] sum p0*t1 [10] sum p1*t0 [11] sum p1*t1

__global__ __launch_bounds__(256, 4) void pit_partials(
    const float* __restrict__ preds, const float* __restrict__ targets,
    float* __restrict__ ws)
{
    const int b = blockIdx.x / CHUNKS;
    const int c = blockIdx.x % CHUNKS;
    const int lane = threadIdx.x & 63;
    const int wave = threadIdx.x >> 6;

    const float4* p0 = (const float4*)(preds   + (size_t)(b * 2 + 0) * TT);
    const float4* p1 = (const float4*)(preds   + (size_t)(b * 2 + 1) * TT);
    const float4* t0 = (const float4*)(targets + (size_t)(b * 2 + 0) * TT);
    const float4* t1 = (const float4*)(targets + (size_t)(b * 2 + 1) * TT);

    float acc[12];
#pragma unroll
    for (int k = 0; k < 12; ++k) acc[k] = 0.f;

    // wave w owns a CONTIGUOUS 5-segment sub-chunk; walking it segment-by-
    // segment rotates the wave's 4KB address phase each iteration ((w+it)&3),
    // breaking the channel camping caused by 1MB row pitch + 4KB loop stride.
    const int base = c * CHUNK + wave * (SEGS_PER_WAVE * 64) + lane;

    // 2-deep software pipeline: preload segment s+1 while consuming s
    float4 a0 = p0[base], a1 = p1[base], b0 = t0[base], b1 = t1[base];
#pragma unroll
    for (int s = 0; s < SEGS_PER_WAVE; ++s) {
        float4 na0, na1, nb0, nb1;
        if (s + 1 < SEGS_PER_WAVE) {
            const int i = base + (s + 1) * 64;
            na0 = p0[i]; na1 = p1[i]; nb0 = t0[i]; nb1 = t1[i];
        }
#pragma unroll
        for (int e = 0; e < 4; ++e) {
            float u0 = (&a0.x)[e], u1 = (&a1.x)[e];
            float v0 = (&b0.x)[e], v1 = (&b1.x)[e];
            acc[0]  += u0;       acc[1]  += u1;
            acc[2]  += v0;       acc[3]  += v1;
            acc[4]  += u0 * u0;  acc[5]  += u1 * u1;
            acc[6]  += v0 * v0;  acc[7]  += v1 * v1;
            acc[8]  += u0 * v0;  acc[9]  += u0 * v1;
            acc[10] += u1 * v0;  acc[11] += u1 * v1;
        }
        a0 = na0; a1 = na1; b0 = nb0; b1 = nb1;
    }

    // wave(64)-level shuffle reduction for all 12 stats
#pragma unroll
    for (int k = 0; k < 12; ++k) {
        float v = acc[k];
        for (int off = 32; off > 0; off >>= 1) v += __shfl_down(v, off);
        acc[k] = v;   // valid in lane 0 of each wave
    }

    __shared__ float lds[4][12];
    if (lane == 0) {
#pragma unroll
        for (int k = 0; k < 12; ++k) lds[wave][k] = acc[k];
    }
    __syncthreads();

    // threads 0..11: sum the 4 wave-partials, plain store (no atomics)
    if (threadIdx.x < 12) {
        float v = lds[0][threadIdx.x] + lds[1][threadIdx.x]
                + lds[2][threadIdx.x] + lds[3][threadIdx.x];
        ws[(size_t)blockIdx.x * 12 + threadIdx.x] = v;
    }
}

// Reduce NBLK x 12 partials -> B x 12 stats -> SI-SNR -> PIT -> scalar loss
__global__ __launch_bounds__(256) void pit_final(
    const float* __restrict__ ws, float* __restrict__ out)
{
    __shared__ float sums[BB * 12];
    __shared__ float bests[BB];

    for (int s = threadIdx.x; s < BB * 12; s += 256) {
        const int b = s / 12;
        const int k = s % 12;
        float v = 0.f;
        const float* base = ws + (size_t)(b * CHUNKS) * 12 + k;
#pragma unroll 10
        for (int c = 0; c < CHUNKS; ++c) v += base[(size_t)c * 12];
        sums[s] = v;
    }
    __syncthreads();

    if (threadIdx.x < BB) {
        const float* w = sums + threadIdx.x * 12;
        const float invT = 1.0f / (float)TT;
        float pp0 = w[4] - w[0] * w[0] * invT;
        float pp1 = w[5] - w[1] * w[1] * invT;
        float tt0 = w[6] - w[2] * w[2] * invT;
        float tt1 = w[7] - w[3] * w[3] * invT;
        float d00 = w[8]  - w[0] * w[2] * invT;
        float d01 = w[9]  - w[0] * w[3] * invT;
        float d10 = w[10] - w[1] * w[2] * invT;
        float d11 = w[11] - w[1] * w[3] * invT;

        auto sisnr = [](float dot, float pp, float tt) -> float {
            float alpha = dot / (tt + EPS);
            float st    = alpha * alpha * tt;
            float noise = pp - 2.0f * alpha * dot + st;
            return 10.0f * log10f((st + EPS) / (noise + EPS));
        };
        float s00 = sisnr(d00, pp0, tt0);
        float s01 = sisnr(d01, pp0, tt1);
        float s10 = sisnr(d10, pp1, tt0);
        float s11 = sisnr(d11, pp1, tt1);

        float perm0 = 0.5f * (s00 + s11);
        float perm1 = 0.5f * (s01 + s10);
        bests[threadIdx.x] = fmaxf(perm0, perm1);
    }
    __syncthreads();

    if (threadIdx.x == 0) {
        float acc = 0.f;
#pragma unroll
        for (int b = 0; b < BB; ++b) acc += bests[b];
        out[0] = -acc / (float)BB;
    }
}

extern "C" void kernel_launch(void* const* d_in, const int* in_sizes, int n_in,
                              void* d_out, int out_size, void* d_ws, size_t ws_size,
                              hipStream_t stream)
{
    const float* preds   = (const float*)d_in[0];
    const float* targets = (const float*)d_in[1];
    float* out = (float*)d_out;
    float* ws  = (float*)d_ws;   // NBLK*12 floats = 76.8 KB scratch

    pit_partials<<<dim3(NBLK), dim3(256), 0, stream>>>(preds, targets, ws);
    pit_final<<<dim3(1), dim3(256), 0, stream>>>(ws, out);
}

// Round 5
// 147.181 us; speedup vs baseline: 1.0007x; 1.0007x over previous
//
#include <hip/hip_runtime.h>

#define EPS 1.1920928955078125e-07f

// Problem constants
#define BB 32
#define TT 256000
#define CHUNKS 50                    // chunks per batch element
#define T4 (TT / 4)                  // 64000 float4 per signal
#define CHUNK (T4 / CHUNKS)          // 1280 float4 per block
#define SEGS 5                       // 5 segments x 64 float4 per wave; 4 waves = 1280
#define NBLK (BB * CHUNKS)           // 1600 blocks

// 12 per-batch statistics (raw sums; zero-meaning folded in at finalize):
// [0] sum p0   [1] sum p1   [2] sum t0   [3] sum t1
// [4] sum p0^2 [5] sum p1^2 [6] sum t0^2 [7] sum t1^2
// [8] sum p0*t0 [9] sum p0*t1 [10] sum p1*t0 [11] sum p1*t1

__global__ __launch_bounds__(256, 4) void pit_partials(
    const float* __restrict__ preds, const float* __restrict__ targets,
    float* __restrict__ ws)
{
    const int b = blockIdx.x / CHUNKS;
    const int c = blockIdx.x % CHUNKS;
    const int lane = threadIdx.x & 63;
    const int wave = threadIdx.x >> 6;

    const float4* p0 = (const float4*)(preds   + (size_t)(b * 2 + 0) * TT);
    const float4* p1 = (const float4*)(preds   + (size_t)(b * 2 + 1) * TT);
    const float4* t0 = (const float4*)(targets + (size_t)(b * 2 + 0) * TT);
    const float4* t1 = (const float4*)(targets + (size_t)(b * 2 + 1) * TT);

    // wave w owns a contiguous 5-segment (5 KB) sub-chunk of the block's chunk
    const int base = c * CHUNK + wave * (SEGS * 64) + lane;

    // ---- phase 1: issue ALL 20 loads back-to-back (20 KB in flight per wave).
    // Stream-major order: each stream's 5 requests are address-sequential.
    float4 rp0[SEGS], rp1[SEGS], rt0[SEGS], rt1[SEGS];
#pragma unroll
    for (int s = 0; s < SEGS; ++s) rp0[s] = p0[base + s * 64];
#pragma unroll
    for (int s = 0; s < SEGS; ++s) rp1[s] = p1[base + s * 64];
#pragma unroll
    for (int s = 0; s < SEGS; ++s) rt0[s] = t0[base + s * 64];
#pragma unroll
    for (int s = 0; s < SEGS; ++s) rt1[s] = t1[base + s * 64];

    // ---- phase 2: accumulate (first-use waits form a descending vmcnt ladder)
    float acc[12];
#pragma unroll
    for (int k = 0; k < 12; ++k) acc[k] = 0.f;

#pragma unroll
    for (int s = 0; s < SEGS; ++s) {
#pragma unroll
        for (int e = 0; e < 4; ++e) {
            float u0 = (&rp0[s].x)[e], u1 = (&rp1[s].x)[e];
            float v0 = (&rt0[s].x)[e], v1 = (&rt1[s].x)[e];
            acc[0]  += u0;       acc[1]  += u1;
            acc[2]  += v0;       acc[3]  += v1;
            acc[4]  += u0 * u0;  acc[5]  += u1 * u1;
            acc[6]  += v0 * v0;  acc[7]  += v1 * v1;
            acc[8]  += u0 * v0;  acc[9]  += u0 * v1;
            acc[10] += u1 * v0;  acc[11] += u1 * v1;
        }
    }

    // wave(64)-level shuffle reduction for all 12 stats
#pragma unroll
    for (int k = 0; k < 12; ++k) {
        float v = acc[k];
        for (int off = 32; off > 0; off >>= 1) v += __shfl_down(v, off);
        acc[k] = v;   // valid in lane 0 of each wave
    }

    __shared__ float lds[4][12];
    if (lane == 0) {
#pragma unroll
        for (int k = 0; k < 12; ++k) lds[wave][k] = acc[k];
    }
    __syncthreads();

    // threads 0..11: sum the 4 wave-partials, plain store (no atomics)
    if (threadIdx.x < 12) {
        float v = lds[0][threadIdx.x] + lds[1][threadIdx.x]
                + lds[2][threadIdx.x] + lds[3][threadIdx.x];
        ws[(size_t)blockIdx.x * 12 + threadIdx.x] = v;
    }
}

// Reduce NBLK x 12 partials -> B x 12 stats -> SI-SNR -> PIT -> scalar loss
__global__ __launch_bounds__(256) void pit_final(
    const float* __restrict__ ws, float* __restrict__ out)
{
    __shared__ float sums[BB * 12];
    __shared__ float bests[BB];

    for (int s = threadIdx.x; s < BB * 12; s += 256) {
        const int b = s / 12;
        const int k = s % 12;
        float v = 0.f;
        const float* base = ws + (size_t)(b * CHUNKS) * 12 + k;
#pragma unroll 10
        for (int c = 0; c < CHUNKS; ++c) v += base[(size_t)c * 12];
        sums[s] = v;
    }
    __syncthreads();

    if (threadIdx.x < BB) {
        const float* w = sums + threadIdx.x * 12;
        const float invT = 1.0f / (float)TT;
        float pp0 = w[4] - w[0] * w[0] * invT;
        float pp1 = w[5] - w[1] * w[1] * invT;
        float tt0 = w[6] - w[2] * w[2] * invT;
        float tt1 = w[7] - w[3] * w[3] * invT;
        float d00 = w[8]  - w[0] * w[2] * invT;
        float d01 = w[9]  - w[0] * w[3] * invT;
        float d10 = w[10] - w[1] * w[2] * invT;
        float d11 = w[11] - w[1] * w[3] * invT;

        auto sisnr = [](float dot, float pp, float tt) -> float {
            float alpha = dot / (tt + EPS);
            float st    = alpha * alpha * tt;
            float noise = pp - 2.0f * alpha * dot + st;
            return 10.0f * log10f((st + EPS) / (noise + EPS));
        };
        float s00 = sisnr(d00, pp0, tt0);
        float s01 = sisnr(d01, pp0, tt1);
        float s10 = sisnr(d10, pp1, tt0);
        float s11 = sisnr(d11, pp1, tt1);

        float perm0 = 0.5f * (s00 + s11);
        float perm1 = 0.5f * (s01 + s10);
        bests[threadIdx.x] = fmaxf(perm0, perm1);
    }
    __syncthreads();

    if (threadIdx.x == 0) {
        float acc = 0.f;
#pragma unroll
        for (int b = 0; b < BB; ++b) acc += bests[b];
        out[0] = -acc / (float)BB;
    }
}

extern "C" void kernel_launch(void* const* d_in, const int* in_sizes, int n_in,
                              void* d_out, int out_size, void* d_ws, size_t ws_size,
                              hipStream_t stream)
{
    const float* preds   = (const float*)d_in[0];
    const float* targets = (const float*)d_in[1];
    float* out = (float*)d_out;
    float* ws  = (float*)d_ws;   // NBLK*12 floats = 76.8 KB scratch

    pit_partials<<<dim3(NBLK), dim3(256), 0, stream>>>(preds, targets, ws);
    pit_final<<<dim3(1), dim3(256), 0, stream>>>(ws, out);
}